// Round 2
// baseline (407.778 us; speedup 1.0000x reference)
//
#include <hip/hip_runtime.h>

// MHA forward. Inputs/output f32 (reference dtype); internal pipeline bf16 MFMA.
// b=2, s=2048, d_model=1024, heads=16, head_dim=64.
// Pipeline: 3x gemm (QKV proj f32->bf16 ws, permuted) -> flash attention (bf16 ws)
//           -> gemm (Ob bf16 x Wo f32 -> f32 out).

typedef __bf16 bf16_t;
typedef __attribute__((ext_vector_type(8))) __bf16 bf16x8;
typedef __attribute__((ext_vector_type(4))) __bf16 bf16x4;
typedef __attribute__((ext_vector_type(4))) float f32x4;

#define MFMA16 __builtin_amdgcn_mfma_f32_16x16x32_bf16

__device__ __forceinline__ bf16_t f2bf(float x) {
  unsigned u = __float_as_uint(x);
  unsigned r = (u + 0x7fffu + ((u >> 16) & 1u)) >> 16;
  unsigned short s = (unsigned short)r;
  return __builtin_bit_cast(bf16_t, s);
}

// C[M,N] = A[M,K] * B[N,K]^T
// ABF/BBF: operand stored as bf16 (else f32, converted during staging).
// MODE 0: C = f32 row-major [M,N] (d_out)
// MODE 1: C = bf16 written as [b,h,s,hd] permute (workspace)
// grid: (N/64, M/128), block 256.
template <int MODE, bool ABF, bool BBF>
__global__ __launch_bounds__(256) void gemm_bt(const void* __restrict__ Av,
                                               const void* __restrict__ Bv,
                                               void* __restrict__ Cv,
                                               int M, int N, int K) {
  constexpr int BM = 128, BN = 64, BK = 64;
  constexpr int LDT = BK + 8;  // +8 bf16 pad: frag reads land 2-way on banks (free)
  __shared__ __align__(16) bf16_t As[BM * LDT];
  __shared__ __align__(16) bf16_t Bs[BN * LDT];

  const int m0 = blockIdx.y * BM;
  const int n0 = blockIdx.x * BN;
  const int tid = threadIdx.x;
  const int lane = tid & 63;
  const int w = tid >> 6;
  const int l15 = lane & 15;
  const int quad = lane >> 4;

  f32x4 acc[2][4];
#pragma unroll
  for (int i = 0; i < 2; i++)
#pragma unroll
    for (int j = 0; j < 4; j++) acc[i][j] = f32x4{0.f, 0.f, 0.f, 0.f};

  for (int k0 = 0; k0 < K; k0 += BK) {
    __syncthreads();
    // ---- stage A tile (128x64) ----
    if (ABF) {
      const bf16_t* A = (const bf16_t*)Av;
#pragma unroll
      for (int r = 0; r < 4; r++) {
        int idx = (r * 256 + tid) * 8;
        int row = idx >> 6, col = idx & 63;
        bf16x8 v = *(const bf16x8*)(A + (long)(m0 + row) * K + k0 + col);
        *(bf16x8*)(&As[row * LDT + col]) = v;
      }
    } else {
      const float* A = (const float*)Av;
#pragma unroll
      for (int r = 0; r < 8; r++) {
        int idx = (r * 256 + tid) * 4;
        int row = idx >> 6, col = idx & 63;
        float4 v = *(const float4*)(A + (long)(m0 + row) * K + k0 + col);
        bf16x4 h;
        h[0] = f2bf(v.x); h[1] = f2bf(v.y); h[2] = f2bf(v.z); h[3] = f2bf(v.w);
        *(bf16x4*)(&As[row * LDT + col]) = h;
      }
    }
    // ---- stage B tile (64x64) ----
    if (BBF) {
      const bf16_t* B = (const bf16_t*)Bv;
#pragma unroll
      for (int r = 0; r < 2; r++) {
        int idx = (r * 256 + tid) * 8;
        int row = idx >> 6, col = idx & 63;
        bf16x8 v = *(const bf16x8*)(B + (long)(n0 + row) * K + k0 + col);
        *(bf16x8*)(&Bs[row * LDT + col]) = v;
      }
    } else {
      const float* B = (const float*)Bv;
#pragma unroll
      for (int r = 0; r < 4; r++) {
        int idx = (r * 256 + tid) * 4;
        int row = idx >> 6, col = idx & 63;
        float4 v = *(const float4*)(B + (long)(n0 + row) * K + k0 + col);
        bf16x4 h;
        h[0] = f2bf(v.x); h[1] = f2bf(v.y); h[2] = f2bf(v.z); h[3] = f2bf(v.w);
        *(bf16x4*)(&Bs[row * LDT + col]) = h;
      }
    }
    __syncthreads();
#pragma unroll
    for (int ks = 0; ks < 2; ks++) {
      bf16x8 af[2], bf[4];
#pragma unroll
      for (int i = 0; i < 2; i++)
        af[i] = *(const bf16x8*)(&As[(w * 32 + i * 16 + l15) * LDT + ks * 32 + quad * 8]);
#pragma unroll
      for (int j = 0; j < 4; j++)
        bf[j] = *(const bf16x8*)(&Bs[(j * 16 + l15) * LDT + ks * 32 + quad * 8]);
#pragma unroll
      for (int i = 0; i < 2; i++)
#pragma unroll
        for (int j = 0; j < 4; j++) acc[i][j] = MFMA16(af[i], bf[j], acc[i][j], 0, 0, 0);
    }
  }

  // epilogue: C/D layout col=lane&15, row=quad*4+reg (m89-verified)
#pragma unroll
  for (int i = 0; i < 2; i++)
#pragma unroll
    for (int j = 0; j < 4; j++) {
      int row = m0 + w * 32 + i * 16 + quad * 4;
      int col = n0 + j * 16 + l15;
#pragma unroll
      for (int r = 0; r < 4; r++) {
        int rr = row + r;
        if (MODE == 0) {
          ((float*)Cv)[(long)rr * N + col] = acc[i][j][r];
        } else {
          int b = rr >> 11, s = rr & 2047;
          int hh = col >> 6, d = col & 63;
          ((bf16_t*)Cv)[(((long)(b * 16 + hh) * 2048 + s) << 6) + d] = f2bf(acc[i][j][r]);
        }
      }
    }
}

// Flash attention, causal. Q,K,V: [32][2048][64] bf16 ws. O: [4096][1024] bf16 ws
// (row = b*2048+s, col = h*64+d). grid (16 qtiles, 32 bh), block 256.
__global__ __launch_bounds__(256) void attn_kernel(const bf16_t* __restrict__ Q,
                                                   const bf16_t* __restrict__ Kp,
                                                   const bf16_t* __restrict__ V,
                                                   bf16_t* __restrict__ O) {
  constexpr int S = 2048, HD = 64, BM = 128, BN = 128;
  constexpr int PS = 136;  // padded stride (2-way bank aliasing = free)
  __shared__ __align__(16) bf16_t Pl[BM * PS];  // P matrix round-trip (C/D -> A layout)
  __shared__ __align__(16) bf16_t Vt[HD * PS];  // V transposed: Vt[d][kv]

  const int bh = blockIdx.y;
  const int qt = blockIdx.x;
  const int q0 = qt * BM;
  const int tid = threadIdx.x;
  const int lane = tid & 63;
  const int w = tid >> 6;
  const int l15 = lane & 15;
  const int quad = lane >> 4;

  const bf16_t* Qb = Q + (long)bh * S * HD;
  const bf16_t* Kb = Kp + (long)bh * S * HD;
  const bf16_t* Vb = V + (long)bh * S * HD;

  // Q fragments for this wave's 32 rows (A-operand layout: m=lane&15, k=quad*8+j)
  bf16x8 qf[2][2];
#pragma unroll
  for (int i = 0; i < 2; i++)
#pragma unroll
    for (int ks = 0; ks < 2; ks++)
      qf[i][ks] = *(const bf16x8*)(Qb + (long)(q0 + w * 32 + i * 16 + l15) * HD + ks * 32 + quad * 8);

  f32x4 Oacc[2][4];
#pragma unroll
  for (int i = 0; i < 2; i++)
#pragma unroll
    for (int n = 0; n < 4; n++) Oacc[i][n] = f32x4{0.f, 0.f, 0.f, 0.f};
  float m_i[2][4], l_i[2][4];
#pragma unroll
  for (int i = 0; i < 2; i++)
#pragma unroll
    for (int r = 0; r < 4; r++) { m_i[i][r] = -1e30f; l_i[i][r] = 0.f; }

  const float scale = 0.125f;  // 1/sqrt(64)

  for (int kt = 0; kt <= qt; kt++) {
    const int kv0 = kt * BN;
    __syncthreads();  // guard Vt reads (P*V) of previous iteration
    // stage V transposed: Vt[d][kv]
#pragma unroll
    for (int r = 0; r < 4; r++) {
      int idx = (r * 256 + tid) * 8;
      int kv = idx >> 6, d = idx & 63;
      bf16x8 v = *(const bf16x8*)(Vb + (long)(kv0 + kv) * HD + d);
#pragma unroll
      for (int j = 0; j < 8; j++) Vt[(d + j) * PS + kv] = v[j];
    }
    __syncthreads();

    // S = Q*K^T for this wave's 32 rows x 128 cols
    f32x4 Sacc[2][8];
#pragma unroll
    for (int i = 0; i < 2; i++)
#pragma unroll
      for (int jt = 0; jt < 8; jt++) Sacc[i][jt] = f32x4{0.f, 0.f, 0.f, 0.f};
#pragma unroll
    for (int jt = 0; jt < 8; jt++) {
      const bf16_t* kr = Kb + (long)(kv0 + jt * 16 + l15) * HD + quad * 8;
      bf16x8 kf0 = *(const bf16x8*)(kr);
      bf16x8 kf1 = *(const bf16x8*)(kr + 32);
#pragma unroll
      for (int i = 0; i < 2; i++) {
        Sacc[i][jt] = MFMA16(qf[i][0], kf0, Sacc[i][jt], 0, 0, 0);
        Sacc[i][jt] = MFMA16(qf[i][1], kf1, Sacc[i][jt], 0, 0, 0);
      }
    }

    // scale + causal mask (only diagonal tile needs it)
#pragma unroll
    for (int i = 0; i < 2; i++)
#pragma unroll
      for (int jt = 0; jt < 8; jt++)
#pragma unroll
        for (int r = 0; r < 4; r++) {
          float s = Sacc[i][jt][r] * scale;
          if (kt == qt) {
            int col = kv0 + jt * 16 + l15;
            int row = q0 + w * 32 + i * 16 + quad * 4 + r;
            if (col > row) s = -1e30f;
          }
          Sacc[i][jt][r] = s;
        }

    // online softmax per row (row lives across the 16 lanes of this quad-group)
#pragma unroll
    for (int i = 0; i < 2; i++)
#pragma unroll
      for (int r = 0; r < 4; r++) {
        float mx = -1e30f;
#pragma unroll
        for (int jt = 0; jt < 8; jt++) mx = fmaxf(mx, Sacc[i][jt][r]);
#pragma unroll
        for (int off = 1; off < 16; off <<= 1) mx = fmaxf(mx, __shfl_xor(mx, off, 64));
        float mnew = fmaxf(m_i[i][r], mx);
        float alpha = __expf(m_i[i][r] - mnew);
        float rs = 0.f;
#pragma unroll
        for (int jt = 0; jt < 8; jt++) {
          float p = __expf(Sacc[i][jt][r] - mnew);
          Sacc[i][jt][r] = p;
          rs += p;
        }
#pragma unroll
        for (int off = 1; off < 16; off <<= 1) rs += __shfl_xor(rs, off, 64);
        l_i[i][r] = l_i[i][r] * alpha + rs;
        m_i[i][r] = mnew;
#pragma unroll
        for (int n = 0; n < 4; n++) Oacc[i][n][r] *= alpha;
      }

    // write P (bf16) to LDS in C/D layout position
#pragma unroll
    for (int i = 0; i < 2; i++)
#pragma unroll
      for (int jt = 0; jt < 8; jt++)
#pragma unroll
        for (int r = 0; r < 4; r++)
          Pl[(w * 32 + i * 16 + quad * 4 + r) * PS + jt * 16 + l15] = f2bf(Sacc[i][jt][r]);
    __syncthreads();  // keep waves in step before Vt gets overwritten next iter

    // O += P * V  (A-frags from Pl, B-frags from Vt)
#pragma unroll
    for (int ks = 0; ks < 4; ks++) {
      bf16x8 af[2], bfv[4];
#pragma unroll
      for (int i = 0; i < 2; i++)
        af[i] = *(const bf16x8*)(&Pl[(w * 32 + i * 16 + l15) * PS + ks * 32 + quad * 8]);
#pragma unroll
      for (int n = 0; n < 4; n++)
        bfv[n] = *(const bf16x8*)(&Vt[(n * 16 + l15) * PS + ks * 32 + quad * 8]);
#pragma unroll
      for (int i = 0; i < 2; i++)
#pragma unroll
        for (int n = 0; n < 4; n++) Oacc[i][n] = MFMA16(af[i], bfv[n], Oacc[i][n], 0, 0, 0);
    }
  }

  // epilogue: O[b*2048+row][h*64 + d]
  const int bb = bh >> 4, hh = bh & 15;
#pragma unroll
  for (int i = 0; i < 2; i++)
#pragma unroll
    for (int n = 0; n < 4; n++)
#pragma unroll
      for (int r = 0; r < 4; r++) {
        int row = q0 + w * 32 + i * 16 + quad * 4 + r;
        float v = Oacc[i][n][r] / l_i[i][r];
        O[(long)(bb * 2048 + row) * 1024 + hh * 64 + n * 16 + l15] = f2bf(v);
      }
}

extern "C" void kernel_launch(void* const* d_in, const int* in_sizes, int n_in,
                              void* d_out, int out_size, void* d_ws, size_t ws_size,
                              hipStream_t stream) {
  const float* x = (const float*)d_in[0];
  const float* Wq = (const float*)d_in[1];
  const float* Wk = (const float*)d_in[2];
  const float* Wv = (const float*)d_in[3];
  const float* Wo = (const float*)d_in[4];
  float* out = (float*)d_out;

  const long SZ = 4096L * 1024;  // 4M bf16 elems per ws buffer
  bf16_t* Qb = (bf16_t*)d_ws;
  bf16_t* Kb = Qb + SZ;
  bf16_t* Vb = Kb + SZ;
  bf16_t* Ob = Vb + SZ;

  dim3 blk(256);
  dim3 gproj(1024 / 64, 4096 / 128);  // (16, 32)
  gemm_bt<1, false, false><<<gproj, blk, 0, stream>>>(x, Wq, Qb, 4096, 1024, 1024);
  gemm_bt<1, false, false><<<gproj, blk, 0, stream>>>(x, Wk, Kb, 4096, 1024, 1024);
  gemm_bt<1, false, false><<<gproj, blk, 0, stream>>>(x, Wv, Vb, 4096, 1024, 1024);
  attn_kernel<<<dim3(16, 32), blk, 0, stream>>>(Qb, Kb, Vb, Ob);
  gemm_bt<0, true, false><<<gproj, blk, 0, stream>>>(Ob, Wo, out, 4096, 1024, 1024);
}

// Round 3
// 288.137 us; speedup vs baseline: 1.4152x; 1.4152x over previous
//
#include <hip/hip_runtime.h>

// MHA forward. Inputs/output f32; internal bf16 MFMA pipeline.
// b=2, s=2048, d_model=1024, heads=16, head_dim=64.
// Fast path (ws >= 48MB):
//   cvt (f32->bf16: x, Wq|Wk|Wv concat, Wo) -> fused QKV gemm128 (global_load_lds,
//   permuted [bh][s][hd] out) -> vtrans (V -> [bh][d][s]) -> attn2 (balanced pairs)
//   -> gemm128 (O x Wo^T -> f32 out).
// Fallback (ws < 48MB): round-2 proven path.

typedef __bf16 bf16_t;
typedef __attribute__((ext_vector_type(8))) __bf16 bf16x8;
typedef __attribute__((ext_vector_type(4))) __bf16 bf16x4;
typedef __attribute__((ext_vector_type(4))) float f32x4;

#define MFMA16 __builtin_amdgcn_mfma_f32_16x16x32_bf16

__device__ __forceinline__ bf16_t f2bf(float x) {
  unsigned u = __float_as_uint(x);
  unsigned r = (u + 0x7fffu + ((u >> 16) & 1u)) >> 16;
  unsigned short s = (unsigned short)r;
  return __builtin_bit_cast(bf16_t, s);
}

// async global->LDS, 16B per lane. LDS dest must be wave-uniform base + lane*16.
__device__ __forceinline__ void gld_lds16(const bf16_t* g, bf16_t* l) {
  __builtin_amdgcn_global_load_lds(
      (const __attribute__((address_space(1))) unsigned int*)g,
      (__attribute__((address_space(3))) unsigned int*)l, 16, 0, 0);
}

// ---------------- convert: x -> Xb, {Wq,Wk,Wv} -> Wqkv concat, Wo -> Wob ----
__global__ __launch_bounds__(256) void cvt_kernel(const float4* __restrict__ x,
                                                  const float4* __restrict__ wq,
                                                  const float4* __restrict__ wk,
                                                  const float4* __restrict__ wv,
                                                  const float4* __restrict__ wo,
                                                  bf16x4* __restrict__ xb,
                                                  bf16x4* __restrict__ wqkv,
                                                  bf16x4* __restrict__ wob) {
  const int NX = (2 * 2048 * 1024) / 4;  // 2,097,152
  const int NW = (1024 * 1024) / 4;      // 262,144 = 2^18
  const int TOT = NX + 4 * NW;
  for (int i = blockIdx.x * 256 + threadIdx.x; i < TOT; i += gridDim.x * 256) {
    const float4* s;
    bf16x4* d;
    if (i < NX) {
      s = x + i; d = xb + i;
    } else {
      int t = i - NX;
      int w = t >> 18;
      int o = t & (NW - 1);
      if (w == 0)      { s = wq + o; d = wqkv + o; }
      else if (w == 1) { s = wk + o; d = wqkv + NW + o; }
      else if (w == 2) { s = wv + o; d = wqkv + 2 * NW + o; }
      else             { s = wo + o; d = wob + o; }
    }
    float4 v = *s;
    bf16x4 h;
    h[0] = f2bf(v.x); h[1] = f2bf(v.y); h[2] = f2bf(v.z); h[3] = f2bf(v.w);
    *d = h;
  }
}

// ---------------- m97-style bf16 GEMM: C[M,N] = A[M,K] * B[N,K]^T -----------
// MODE 0: f32 row-major out. MODE 1: QKV split + permute to [b,h,s,hd].
// 128x128x64 tile, 4 waves 2x2, global_load_lds width 16. grid (N/128, M/128).
template <int MODE>
__global__ __launch_bounds__(256) void gemm128(const bf16_t* __restrict__ A,
                                               const bf16_t* __restrict__ B,
                                               float* __restrict__ Cf,
                                               bf16_t* __restrict__ Qo,
                                               bf16_t* __restrict__ Ko,
                                               bf16_t* __restrict__ Vo,
                                               int M, int N, int K) {
  __shared__ __align__(16) bf16_t As[128 * 64];
  __shared__ __align__(16) bf16_t Bs[128 * 64];
  const int m0 = blockIdx.y * 128, n0 = blockIdx.x * 128;
  const int tid = threadIdx.x, lane = tid & 63;
  const int l15 = lane & 15, quad = lane >> 4;
  const int w = tid >> 6;
  const int wr = (w >> 1) * 64, wc = (w & 1) * 64;

  f32x4 acc[4][4];
#pragma unroll
  for (int i = 0; i < 4; i++)
#pragma unroll
    for (int j = 0; j < 4; j++) acc[i][j] = f32x4{0.f, 0.f, 0.f, 0.f};

  for (int k0 = 0; k0 < K; k0 += 64) {
    __syncthreads();
#pragma unroll
    for (int r = 0; r < 4; r++) {
      int c = r * 256 + tid;
      gld_lds16(A + (long)(m0 + (c >> 3)) * K + k0 + (c & 7) * 8, As + c * 8);
    }
#pragma unroll
    for (int r = 0; r < 4; r++) {
      int c = r * 256 + tid;
      gld_lds16(B + (long)(n0 + (c >> 3)) * K + k0 + (c & 7) * 8, Bs + c * 8);
    }
    __syncthreads();
#pragma unroll
    for (int ks = 0; ks < 2; ks++) {
      bf16x8 af[4], bv[4];
#pragma unroll
      for (int i = 0; i < 4; i++)
        af[i] = *(const bf16x8*)(As + (wr + i * 16 + l15) * 64 + ks * 32 + quad * 8);
#pragma unroll
      for (int j = 0; j < 4; j++)
        bv[j] = *(const bf16x8*)(Bs + (wc + j * 16 + l15) * 64 + ks * 32 + quad * 8);
#pragma unroll
      for (int i = 0; i < 4; i++)
#pragma unroll
        for (int j = 0; j < 4; j++) acc[i][j] = MFMA16(af[i], bv[j], acc[i][j], 0, 0, 0);
    }
  }

  if (MODE == 0) {
#pragma unroll
    for (int i = 0; i < 4; i++)
#pragma unroll
      for (int j = 0; j < 4; j++) {
        int col = n0 + wc + j * 16 + l15;
#pragma unroll
        for (int r = 0; r < 4; r++) {
          int row = m0 + wr + i * 16 + quad * 4 + r;
          Cf[(long)row * N + col] = acc[i][j][r];
        }
      }
  } else {
    const int mat = n0 >> 10;  // block entirely within one of Q/K/V (128 | 1024)
    bf16_t* dst = (mat == 0) ? Qo : (mat == 1) ? Ko : Vo;
#pragma unroll
    for (int i = 0; i < 4; i++)
#pragma unroll
      for (int j = 0; j < 4; j++) {
        int col = (n0 & 1023) + wc + j * 16 + l15;
        int head = col >> 6, hd = col & 63;
#pragma unroll
        for (int r = 0; r < 4; r++) {
          int row = m0 + wr + i * 16 + quad * 4 + r;
          int b = row >> 11, s = row & 2047;
          dst[(((long)(b * 16 + head) * 2048 + s) << 6) + hd] = f2bf(acc[i][j][r]);
        }
      }
  }
}

// ---------------- V transpose: [bh][s][hd] -> [bh][hd][s] -------------------
__global__ __launch_bounds__(256) void vtrans(const bf16_t* __restrict__ V,
                                              bf16_t* __restrict__ Vt) {
  __shared__ bf16_t Tl[64 * 72];
  const int bh = blockIdx.y, s0 = blockIdx.x * 64;
  const int tid = threadIdx.x;
  const bf16_t* Vb = V + ((long)bh * 2048 + s0) * 64;
#pragma unroll
  for (int p = 0; p < 2; p++) {
    int c = p * 256 + tid;
    int r = c >> 3, h = (c & 7) * 8;
    *(bf16x8*)(Tl + r * 72 + h) = *(const bf16x8*)(Vb + r * 64 + h);
  }
  __syncthreads();
  bf16_t* Vo = Vt + (long)bh * 64 * 2048 + s0;
#pragma unroll
  for (int p = 0; p < 2; p++) {
    int c = p * 256 + tid;
    int d = c >> 3, so = (c & 7) * 8;
    bf16x8 v;
#pragma unroll
    for (int u = 0; u < 8; u++) v[u] = Tl[(so + u) * 72 + d];
    *(bf16x8*)(Vo + (long)d * 2048 + so) = v;
  }
}

// ---------------- balanced flash attention ----------------------------------
// Q,K: [32][2048][64]; Vt: [32][64][2048]; O: [4096][1024].
// grid (16 pairs, 32 bh); block 256. Block p does q-tiles {p, 31-p} (BM=64),
// exactly 17 x 64x128 units each. Wave w owns 16 rows.
__global__ __launch_bounds__(256, 4) void attn2(const bf16_t* __restrict__ Q,
                                                const bf16_t* __restrict__ Kp,
                                                const bf16_t* __restrict__ Vt,
                                                bf16_t* __restrict__ O) {
  constexpr int PS = 136;
  __shared__ __align__(16) bf16_t Vl[64 * 128];  // V^T tile [d][kv], unpadded (gld_lds)
  __shared__ __align__(16) bf16_t Pl[64 * PS];   // P round-trip (C/D -> A layout)
  const int bh = blockIdx.y, p = blockIdx.x;
  const int tid = threadIdx.x, lane = tid & 63;
  const int l15 = lane & 15, quad = lane >> 4;
  const int w = tid >> 6;
  const bf16_t* Qb = Q + (long)bh * 2048 * 64;
  const bf16_t* Kb = Kp + (long)bh * 2048 * 64;
  const bf16_t* Vg = Vt + (long)bh * 64 * 2048;
  const int bb = bh >> 4, hh = bh & 15;
  const float scale = 0.125f;  // 1/sqrt(64)

  for (int t = 0; t < 2; t++) {
    const int qt = (t == 0) ? p : (31 - p);
    const int q0 = qt * 64;
    const int nkt = (qt >> 1) + 1;

    bf16x8 qf[2];
#pragma unroll
    for (int ks = 0; ks < 2; ks++)
      qf[ks] = *(const bf16x8*)(Qb + (long)(q0 + w * 16 + l15) * 64 + ks * 32 + quad * 8);

    f32x4 Oacc[4];
    float m_i[4], l_i[4];
#pragma unroll
    for (int n = 0; n < 4; n++) Oacc[n] = f32x4{0.f, 0.f, 0.f, 0.f};
#pragma unroll
    for (int r = 0; r < 4; r++) { m_i[r] = -1e30f; l_i[r] = 0.f; }

    for (int kt = 0; kt < nkt; kt++) {
      const int kv0 = kt * 128;
      const bool lastt = (kt == nkt - 1);
      int jtmax = 8, ksmax = 4;
      if (lastt && !(qt & 1)) { jtmax = 4; ksmax = 2; }  // upper half fully masked

      __syncthreads();  // prev iteration's PV reads of Vl done
#pragma unroll
      for (int r = 0; r < 4; r++) {
        int c = r * 256 + tid;
        gld_lds16(Vg + (long)(c >> 4) * 2048 + kv0 + (c & 15) * 8, Vl + c * 8);
      }
      __syncthreads();

      // S = Q K^T (this wave's 16 rows x up to 128 cols)
      f32x4 S[8];
#pragma unroll
      for (int jt = 0; jt < 8; jt++) S[jt] = f32x4{0.f, 0.f, 0.f, 0.f};
#pragma unroll
      for (int jt = 0; jt < 8; jt++)
        if (jt < jtmax) {
          const bf16_t* kr = Kb + (long)(kv0 + jt * 16 + l15) * 64 + quad * 8;
          bf16x8 k0v = *(const bf16x8*)kr;
          bf16x8 k1v = *(const bf16x8*)(kr + 32);
          S[jt] = MFMA16(qf[0], k0v, S[jt], 0, 0, 0);
          S[jt] = MFMA16(qf[1], k1v, S[jt], 0, 0, 0);
        }

      const int rowb = q0 + w * 16 + quad * 4;
#pragma unroll
      for (int jt = 0; jt < 8; jt++)
        if (jt < jtmax) {
          int col = kv0 + jt * 16 + l15;
#pragma unroll
          for (int r = 0; r < 4; r++) {
            float s = S[jt][r] * scale;
            if (lastt && col > rowb + r) s = -1e30f;
            S[jt][r] = s;
          }
        }

      // online softmax; each row's 16 cols live on the 16 lanes of this quad group
#pragma unroll
      for (int r = 0; r < 4; r++) {
        float mx = -1e30f;
#pragma unroll
        for (int jt = 0; jt < 8; jt++)
          if (jt < jtmax) mx = fmaxf(mx, S[jt][r]);
#pragma unroll
        for (int off = 1; off < 16; off <<= 1) mx = fmaxf(mx, __shfl_xor(mx, off, 64));
        float mnew = fmaxf(m_i[r], mx);
        float alpha = __expf(m_i[r] - mnew);
        float rs = 0.f;
#pragma unroll
        for (int jt = 0; jt < 8; jt++)
          if (jt < jtmax) {
            float pv = __expf(S[jt][r] - mnew);
            S[jt][r] = pv;
            rs += pv;
          }
#pragma unroll
        for (int off = 1; off < 16; off <<= 1) rs += __shfl_xor(rs, off, 64);
        l_i[r] = l_i[r] * alpha + rs;
        m_i[r] = mnew;
#pragma unroll
        for (int n = 0; n < 4; n++) Oacc[n][r] *= alpha;
      }

      // P -> LDS (C/D layout position); rows w*16..w*16+15 are wave-private
#pragma unroll
      for (int jt = 0; jt < 8; jt++)
        if (jt < jtmax)
#pragma unroll
          for (int r = 0; r < 4; r++)
            Pl[(w * 16 + quad * 4 + r) * PS + jt * 16 + l15] = f2bf(S[jt][r]);

      // O += P V (A-frags from own Pl rows; no barrier needed before reads)
#pragma unroll
      for (int ks = 0; ks < 4; ks++)
        if (ks < ksmax) {
          bf16x8 af = *(const bf16x8*)(Pl + (w * 16 + l15) * PS + ks * 32 + quad * 8);
          bf16x8 bv[4];
#pragma unroll
          for (int n = 0; n < 4; n++)
            bv[n] = *(const bf16x8*)(Vl + (n * 16 + l15) * 128 + ks * 32 + quad * 8);
#pragma unroll
          for (int n = 0; n < 4; n++) Oacc[n] = MFMA16(af, bv[n], Oacc[n], 0, 0, 0);
        }
    }

#pragma unroll
    for (int n = 0; n < 4; n++)
#pragma unroll
      for (int r = 0; r < 4; r++) {
        int row = q0 + w * 16 + quad * 4 + r;
        O[((long)bb * 2048 + row) * 1024 + hh * 64 + n * 16 + l15] = f2bf(Oacc[n][r] / l_i[r]);
      }
  }
}

// ======================= legacy (round-2) fallback path ======================
template <int MODE, bool ABF, bool BBF>
__global__ __launch_bounds__(256) void gemm_bt(const void* __restrict__ Av,
                                               const void* __restrict__ Bv,
                                               void* __restrict__ Cv,
                                               int M, int N, int K) {
  constexpr int BM = 128, BN = 64, BK = 64;
  constexpr int LDT = BK + 8;
  __shared__ __align__(16) bf16_t As[BM * LDT];
  __shared__ __align__(16) bf16_t Bs[BN * LDT];
  const int m0 = blockIdx.y * BM, n0 = blockIdx.x * BN;
  const int tid = threadIdx.x, lane = tid & 63, w = tid >> 6;
  const int l15 = lane & 15, quad = lane >> 4;
  f32x4 acc[2][4];
#pragma unroll
  for (int i = 0; i < 2; i++)
#pragma unroll
    for (int j = 0; j < 4; j++) acc[i][j] = f32x4{0.f, 0.f, 0.f, 0.f};
  for (int k0 = 0; k0 < K; k0 += BK) {
    __syncthreads();
    if (ABF) {
      const bf16_t* A = (const bf16_t*)Av;
#pragma unroll
      for (int r = 0; r < 4; r++) {
        int idx = (r * 256 + tid) * 8;
        int row = idx >> 6, col = idx & 63;
        *(bf16x8*)(&As[row * LDT + col]) = *(const bf16x8*)(A + (long)(m0 + row) * K + k0 + col);
      }
    } else {
      const float* A = (const float*)Av;
#pragma unroll
      for (int r = 0; r < 8; r++) {
        int idx = (r * 256 + tid) * 4;
        int row = idx >> 6, col = idx & 63;
        float4 v = *(const float4*)(A + (long)(m0 + row) * K + k0 + col);
        bf16x4 h;
        h[0] = f2bf(v.x); h[1] = f2bf(v.y); h[2] = f2bf(v.z); h[3] = f2bf(v.w);
        *(bf16x4*)(&As[row * LDT + col]) = h;
      }
    }
    if (BBF) {
      const bf16_t* B = (const bf16_t*)Bv;
#pragma unroll
      for (int r = 0; r < 2; r++) {
        int idx = (r * 256 + tid) * 8;
        int row = idx >> 6, col = idx & 63;
        *(bf16x8*)(&Bs[row * LDT + col]) = *(const bf16x8*)(B + (long)(n0 + row) * K + k0 + col);
      }
    } else {
      const float* B = (const float*)Bv;
#pragma unroll
      for (int r = 0; r < 4; r++) {
        int idx = (r * 256 + tid) * 4;
        int row = idx >> 6, col = idx & 63;
        float4 v = *(const float4*)(B + (long)(n0 + row) * K + k0 + col);
        bf16x4 h;
        h[0] = f2bf(v.x); h[1] = f2bf(v.y); h[2] = f2bf(v.z); h[3] = f2bf(v.w);
        *(bf16x4*)(&Bs[row * LDT + col]) = h;
      }
    }
    __syncthreads();
#pragma unroll
    for (int ks = 0; ks < 2; ks++) {
      bf16x8 af[2], bf[4];
#pragma unroll
      for (int i = 0; i < 2; i++)
        af[i] = *(const bf16x8*)(&As[(w * 32 + i * 16 + l15) * LDT + ks * 32 + quad * 8]);
#pragma unroll
      for (int j = 0; j < 4; j++)
        bf[j] = *(const bf16x8*)(&Bs[(j * 16 + l15) * LDT + ks * 32 + quad * 8]);
#pragma unroll
      for (int i = 0; i < 2; i++)
#pragma unroll
        for (int j = 0; j < 4; j++) acc[i][j] = MFMA16(af[i], bf[j], acc[i][j], 0, 0, 0);
    }
  }
#pragma unroll
  for (int i = 0; i < 2; i++)
#pragma unroll
    for (int j = 0; j < 4; j++) {
      int row = m0 + w * 32 + i * 16 + quad * 4;
      int col = n0 + j * 16 + l15;
#pragma unroll
      for (int r = 0; r < 4; r++) {
        int rr = row + r;
        if (MODE == 0) {
          ((float*)Cv)[(long)rr * N + col] = acc[i][j][r];
        } else {
          int b = rr >> 11, s = rr & 2047;
          int hh = col >> 6, d = col & 63;
          ((bf16_t*)Cv)[(((long)(b * 16 + hh) * 2048 + s) << 6) + d] = f2bf(acc[i][j][r]);
        }
      }
    }
}

__global__ __launch_bounds__(256) void attn_legacy(const bf16_t* __restrict__ Q,
                                                   const bf16_t* __restrict__ Kp,
                                                   const bf16_t* __restrict__ V,
                                                   bf16_t* __restrict__ O) {
  constexpr int S = 2048, HD = 64, BM = 128;
  constexpr int PS = 136;
  __shared__ __align__(16) bf16_t Pl[BM * PS];
  __shared__ __align__(16) bf16_t Vt[HD * PS];
  const int bh = blockIdx.y, qt = blockIdx.x, q0 = qt * BM;
  const int tid = threadIdx.x, lane = tid & 63, w = tid >> 6;
  const int l15 = lane & 15, quad = lane >> 4;
  const bf16_t* Qb = Q + (long)bh * S * HD;
  const bf16_t* Kb = Kp + (long)bh * S * HD;
  const bf16_t* Vb = V + (long)bh * S * HD;
  bf16x8 qf[2][2];
#pragma unroll
  for (int i = 0; i < 2; i++)
#pragma unroll
    for (int ks = 0; ks < 2; ks++)
      qf[i][ks] = *(const bf16x8*)(Qb + (long)(q0 + w * 32 + i * 16 + l15) * HD + ks * 32 + quad * 8);
  f32x4 Oacc[2][4];
#pragma unroll
  for (int i = 0; i < 2; i++)
#pragma unroll
    for (int n = 0; n < 4; n++) Oacc[i][n] = f32x4{0.f, 0.f, 0.f, 0.f};
  float m_i[2][4], l_i[2][4];
#pragma unroll
  for (int i = 0; i < 2; i++)
#pragma unroll
    for (int r = 0; r < 4; r++) { m_i[i][r] = -1e30f; l_i[i][r] = 0.f; }
  const float scale = 0.125f;
  for (int kt = 0; kt <= qt; kt++) {
    const int kv0 = kt * 128;
    __syncthreads();
#pragma unroll
    for (int r = 0; r < 4; r++) {
      int idx = (r * 256 + tid) * 8;
      int kv = idx >> 6, d = idx & 63;
      bf16x8 v = *(const bf16x8*)(Vb + (long)(kv0 + kv) * HD + d);
#pragma unroll
      for (int j = 0; j < 8; j++) Vt[(d + j) * PS + kv] = v[j];
    }
    __syncthreads();
    f32x4 Sacc[2][8];
#pragma unroll
    for (int i = 0; i < 2; i++)
#pragma unroll
      for (int jt = 0; jt < 8; jt++) Sacc[i][jt] = f32x4{0.f, 0.f, 0.f, 0.f};
#pragma unroll
    for (int jt = 0; jt < 8; jt++) {
      const bf16_t* kr = Kb + (long)(kv0 + jt * 16 + l15) * HD + quad * 8;
      bf16x8 kf0 = *(const bf16x8*)(kr);
      bf16x8 kf1 = *(const bf16x8*)(kr + 32);
#pragma unroll
      for (int i = 0; i < 2; i++) {
        Sacc[i][jt] = MFMA16(qf[i][0], kf0, Sacc[i][jt], 0, 0, 0);
        Sacc[i][jt] = MFMA16(qf[i][1], kf1, Sacc[i][jt], 0, 0, 0);
      }
    }
#pragma unroll
    for (int i = 0; i < 2; i++)
#pragma unroll
      for (int jt = 0; jt < 8; jt++)
#pragma unroll
        for (int r = 0; r < 4; r++) {
          float s = Sacc[i][jt][r] * scale;
          if (kt == qt) {
            int col = kv0 + jt * 16 + l15;
            int row = q0 + w * 32 + i * 16 + quad * 4 + r;
            if (col > row) s = -1e30f;
          }
          Sacc[i][jt][r] = s;
        }
#pragma unroll
    for (int i = 0; i < 2; i++)
#pragma unroll
      for (int r = 0; r < 4; r++) {
        float mx = -1e30f;
#pragma unroll
        for (int jt = 0; jt < 8; jt++) mx = fmaxf(mx, Sacc[i][jt][r]);
#pragma unroll
        for (int off = 1; off < 16; off <<= 1) mx = fmaxf(mx, __shfl_xor(mx, off, 64));
        float mnew = fmaxf(m_i[i][r], mx);
        float alpha = __expf(m_i[i][r] - mnew);
        float rs = 0.f;
#pragma unroll
        for (int jt = 0; jt < 8; jt++) {
          float pv = __expf(Sacc[i][jt][r] - mnew);
          Sacc[i][jt][r] = pv;
          rs += pv;
        }
#pragma unroll
        for (int off = 1; off < 16; off <<= 1) rs += __shfl_xor(rs, off, 64);
        l_i[i][r] = l_i[i][r] * alpha + rs;
        m_i[i][r] = mnew;
#pragma unroll
        for (int n = 0; n < 4; n++) Oacc[i][n][r] *= alpha;
      }
#pragma unroll
    for (int i = 0; i < 2; i++)
#pragma unroll
      for (int jt = 0; jt < 8; jt++)
#pragma unroll
        for (int r = 0; r < 4; r++)
          Pl[(w * 32 + i * 16 + quad * 4 + r) * PS + jt * 16 + l15] = f2bf(Sacc[i][jt][r]);
    __syncthreads();
#pragma unroll
    for (int ks = 0; ks < 4; ks++) {
      bf16x8 af[2], bfv[4];
#pragma unroll
      for (int i = 0; i < 2; i++)
        af[i] = *(const bf16x8*)(&Pl[(w * 32 + i * 16 + l15) * PS + ks * 32 + quad * 8]);
#pragma unroll
      for (int n = 0; n < 4; n++)
        bfv[n] = *(const bf16x8*)(&Vt[(n * 16 + l15) * PS + ks * 32 + quad * 8]);
#pragma unroll
      for (int i = 0; i < 2; i++)
#pragma unroll
        for (int n = 0; n < 4; n++) Oacc[i][n] = MFMA16(af[i], bfv[n], Oacc[i][n], 0, 0, 0);
    }
  }
  const int bb = bh >> 4, hh = bh & 15;
#pragma unroll
  for (int i = 0; i < 2; i++)
#pragma unroll
    for (int n = 0; n < 4; n++)
#pragma unroll
      for (int r = 0; r < 4; r++) {
        int row = q0 + w * 32 + i * 16 + quad * 4 + r;
        O[(long)(bb * 2048 + row) * 1024 + hh * 64 + n * 16 + l15] = f2bf(Oacc[i][n][r] / l_i[i][r]);
      }
}

// ============================================================================
extern "C" void kernel_launch(void* const* d_in, const int* in_sizes, int n_in,
                              void* d_out, int out_size, void* d_ws, size_t ws_size,
                              hipStream_t stream) {
  const float* x = (const float*)d_in[0];
  const float* Wq = (const float*)d_in[1];
  const float* Wk = (const float*)d_in[2];
  const float* Wv = (const float*)d_in[3];
  const float* Wo = (const float*)d_in[4];
  float* out = (float*)d_out;

  const long M4 = 4L * 1024 * 1024;  // 4M bf16 elems = 8MB
  dim3 blk(256);

  if (ws_size >= 48u * 1024 * 1024) {
    bf16_t* Qb = (bf16_t*)d_ws;      // [32][2048][64]
    bf16_t* Kb = Qb + M4;
    bf16_t* Vb = Kb + M4;            // reused as Ob after vtrans
    bf16_t* Vtg = Vb + M4;           // [32][64][2048]
    bf16_t* Xb = Vtg + M4;           // [4096][1024]
    bf16_t* Wqkv = Xb + M4;          // [3072][1024]
    bf16_t* Wob = Wqkv + 3L * 1024 * 1024;  // [1024][1024]

    cvt_kernel<<<4096, blk, 0, stream>>>((const float4*)x, (const float4*)Wq,
                                         (const float4*)Wk, (const float4*)Wv,
                                         (const float4*)Wo, (bf16x4*)Xb,
                                         (bf16x4*)Wqkv, (bf16x4*)Wob);
    gemm128<1><<<dim3(24, 32), blk, 0, stream>>>(Xb, Wqkv, nullptr, Qb, Kb, Vb,
                                                 4096, 3072, 1024);
    vtrans<<<dim3(32, 32), blk, 0, stream>>>(Vb, Vtg);
    bf16_t* Ob = Vb;  // alias: Vb dead after vtrans
    attn2<<<dim3(16, 32), blk, 0, stream>>>(Qb, Kb, Vtg, Ob);
    gemm128<0><<<dim3(8, 32), blk, 0, stream>>>(Ob, Wob, out, nullptr, nullptr, nullptr,
                                                4096, 1024, 1024);
  } else {
    // proven round-2 path (32MB ws)
    bf16_t* Qb = (bf16_t*)d_ws;
    bf16_t* Kb = Qb + M4;
    bf16_t* Vb = Kb + M4;
    bf16_t* Ob = Vb + M4;
    dim3 gproj(1024 / 64, 4096 / 128);
    gemm_bt<1, false, false><<<gproj, blk, 0, stream>>>(x, Wq, Qb, 4096, 1024, 1024);
    gemm_bt<1, false, false><<<gproj, blk, 0, stream>>>(x, Wk, Kb, 4096, 1024, 1024);
    gemm_bt<1, false, false><<<gproj, blk, 0, stream>>>(x, Wv, Vb, 4096, 1024, 1024);
    attn_legacy<<<dim3(16, 32), blk, 0, stream>>>(Qb, Kb, Vb, Ob);
    gemm_bt<0, true, false><<<gproj, blk, 0, stream>>>(Ob, Wo, out, 4096, 1024, 1024);
  }
}